// Round 4
// baseline (261.120 us; speedup 1.0000x reference)
//
#include <hip/hip_runtime.h>
#include <hip/hip_bf16.h>
#include <math.h>

// AdAct piecewise-linear activation.
// R1: 83us @2.4TB/s latency-bound (1 load in flight).
// R3: MLP burst of 8 loads -> still 83us: one chunk per block, phase-sync'd
//     burst/drain — memory idle during compute. VALUBusy 21%, HBM 30%.
// R4: persistent blocks + software pipeline (double-buffered stages of
//     PER=4 float4/thread). Loads of stage k+1 in flight while computing
//     stage k -> continuous memory flow. grid=2048 (8 blk/CU = 32-wave cap,
//     LDS 128KB/CU), __launch_bounds__(256,8) keeps VGPR<=64 for 8 waves/SIMD.
// Numerics unchanged from R3 (affine LDS table; x*(1/delta) bin select).

#define BLOCK 256
#define PER 4                       // float4s per thread per stage

typedef float vfloat4 __attribute__((ext_vector_type(4)));

__global__ __launch_bounds__(BLOCK, 8) void adact_kernel(
    const float* __restrict__ x,
    const float* __restrict__ ns,
    const float* __restrict__ a,
    float* __restrict__ out,
    int n, int H)
{
    extern __shared__ float smem[];
    float*  s_ns  = smem;                      // H floats
    float*  s_a   = smem + H;                  // H floats
    float2* s_tab = (float2*)(smem + 2 * H);   // H float2 (A,B)

    for (int i = threadIdx.x; i < H; i += BLOCK) {
        s_ns[i] = ns[i];
        s_a[i]  = a[i];
    }
    __syncthreads();

    const float r       = s_ns[0];
    const float s       = s_ns[H - 1];
    const float delta   = s_ns[1] - s_ns[0];
    const float rd      = 1.0f / delta;
    const float a_first = s_a[0];
    const float a_last  = s_a[H - 1];
    const int bmin = (int)ceilf(r * rd) - 1;

    // Build affine table, replicating reference index math per bin
    // (incl. m2 negative-wrap and denom==0 guard).
    for (int b = threadIdx.x; b < H; b += BLOCK) {
        int m1_raw = bmin + b;
        int m1 = m1_raw;
        if (m1 < 0) m1 = 0;
        if (m1 > H - 1) m1 = H - 1;
        int m2 = m1_raw + 1;
        if (m2 >= H) m2 = H - 1;
        if (m2 < 0)  m2 += H;
        if (m2 < 0)  m2 = 0;
        if (m2 > H - 1) m2 = H - 1;
        float ns1 = s_ns[m1], ns2 = s_ns[m2];
        float a1  = s_a[m1],  a2  = s_a[m2];
        float denom = ns2 - ns1;
        if (denom == 0.0f) denom = 1.0f;       // -> A=B=0, interp=0 exactly
        float Bc = (a2 - a1) / denom;
        float Ac = (a1 * ns2 - a2 * ns1) / denom;
        s_tab[b] = make_float2(Ac, Bc);
    }
    __syncthreads();

    auto eval = [&](float xv) -> float {
        int b = (int)ceilf(xv * rd) - 1 - bmin;
        b = b < 0 ? 0 : (b > H - 1 ? H - 1 : b);
        float2 c = s_tab[b];
        float o = fmaf(c.y, xv, c.x);
        if (xv < r) o = a_first;
        if (xv > s) o = a_last;
        return o;
    };

    const int n4         = n >> 2;
    const int tid        = threadIdx.x;
    const int stage_span = BLOCK * PER;                         // f4 per stage
    const int tot_stages = (n4 + stage_span - 1) / stage_span;
    const int per_blk    = (tot_stages + gridDim.x - 1) / gridDim.x;
    const int st_first   = blockIdx.x * per_blk;
    int st_last          = st_first + per_blk;                  // exclusive
    if (st_last > tot_stages) st_last = tot_stages;
    const int nst        = st_last - st_first;

    const vfloat4* __restrict__ x4 = (const vfloat4*)x;
    vfloat4* __restrict__ o4       = (vfloat4*)out;

    // Fast path: this block's whole range is in-bounds (true when stage_span
    // divides n4 evenly — the actual benchmark case).
    const bool full = ((long)st_last * stage_span) <= (long)n4;

    if (nst > 0 && full) {
        vfloat4 buf[2][PER];
        long base0 = (long)st_first * stage_span + tid;
        #pragma unroll
        for (int k = 0; k < PER; k++)
            buf[0][k] = x4[base0 + k * BLOCK];

        for (int st = 0; st < nst; st++) {
            const int cur = st & 1, nxt = cur ^ 1;
            long base_n = (long)(st_first + st + 1) * stage_span + tid;
            if (st + 1 < nst) {
                #pragma unroll
                for (int k = 0; k < PER; k++)
                    buf[nxt][k] = x4[base_n + k * BLOCK];
            }
            long base_c = (long)(st_first + st) * stage_span + tid;
            #pragma unroll
            for (int k = 0; k < PER; k++) {
                vfloat4 v = buf[cur][k];
                vfloat4 ov;
                ov.x = eval(v.x);
                ov.y = eval(v.y);
                ov.z = eval(v.z);
                ov.w = eval(v.w);
                __builtin_nontemporal_store(ov, &o4[base_c + k * BLOCK]);
            }
        }
    } else if (nst > 0) {
        // Ragged path: per-f4 bounds guards (rare).
        for (int st = 0; st < nst; st++) {
            long base_c = (long)(st_first + st) * stage_span + tid;
            #pragma unroll
            for (int k = 0; k < PER; k++) {
                long idx = base_c + k * BLOCK;
                if (idx < n4) {
                    vfloat4 v = x4[idx];
                    vfloat4 ov;
                    ov.x = eval(v.x);
                    ov.y = eval(v.y);
                    ov.z = eval(v.z);
                    ov.w = eval(v.w);
                    __builtin_nontemporal_store(ov, &o4[idx]);
                }
            }
        }
    }

    // Tail (n % 4 elements).
    const int rem  = n & 3;
    const int gtid = blockIdx.x * BLOCK + threadIdx.x;
    if (gtid < rem) {
        int i = (n4 << 2) + gtid;
        out[i] = eval(x[i]);
    }
}

extern "C" void kernel_launch(void* const* d_in, const int* in_sizes, int n_in,
                              void* d_out, int out_size, void* d_ws, size_t ws_size,
                              hipStream_t stream) {
    const float* x  = (const float*)d_in[0];
    const float* ns = (const float*)d_in[1];
    const float* a  = (const float*)d_in[2];
    float* out = (float*)d_out;
    const int n = in_sizes[0];
    const int H = in_sizes[1];

    const int grid = 2048;          // 8 blocks/CU = 32-wave cap; LDS 128KB/CU
    size_t shmem = (size_t)H * 16;  // ns + a + float2 table
    adact_kernel<<<grid, BLOCK, shmem, stream>>>(x, ns, a, out, n, H);
}